// Round 2
// baseline (981.317 us; speedup 1.0000x reference)
//
#include <hip/hip_runtime.h>
#include <hip/hip_cooperative_groups.h>
#include <math.h>

namespace cg = cooperative_groups;

#define NIMG 116          // 4*29 images
#define TW 118            // output tile width  (phase-1 columns = TW+10 = 128)
#define TH 16             // output tile height (strips of 8 rows, 2 strips)

// 11-tap Gaussian (size=11, sigma=1.5), fp32 values matching the reference.
static constexpr float W[11] = {
    0.00102838f, 0.00759876f, 0.03600078f, 0.10936075f, 0.21300554f,
    0.26601172f, 0.21300554f, 0.10936075f, 0.03600078f, 0.00759876f,
    0.00102838f};

__device__ __forceinline__ float frcp(float x) {
    return __builtin_amdgcn_rcpf(x);
}

__device__ __forceinline__ float fsig(float x) {
    float e = __builtin_amdgcn_exp2f(x * -1.4426950408889634f);
    return frcp(1.0f + e);
}

// ---------------------------------------------------------------------------
// Per-tile SSIM body (identical math to the 421 µs 5-kernel version, R0 form:
// sched_barrier fence only, no keep-alive asm — R1 measured keep-alives cost
// ~5 µs on level 0 with no VGPR change; VGPR=56 already holds all 36 loads).
// Phase 1: batch-load 18 rows/thread, vertical Gaussian of {X,Y,XX,(YY),XY};
// fused 2x2 pool from live registers. Phase 2: horizontal Gaussian from LDS
// via swizzled float4 reads + SSIM map + block reduction + atomicAdd.
// SKIPYY: binary targets -> filter(YY)==filter(Y). NARROW: N<=128, one x-tile.
// LDS padded to 40960 B -> exactly 4 blocks/CU (R4: locality beats occupancy).
// ---------------------------------------------------------------------------
template <int N, int M, bool SIG, bool POOL, bool SKIPYY, bool NARROW>
__device__ __forceinline__ void ssim_tile(
    const float* __restrict__ X, const float* __restrict__ Y,
    float* __restrict__ accSsim, float* __restrict__ accCs,
    float* __restrict__ poolX, float* __restrict__ poolY,
    int img, int bx, int by, float* smem) {
    constexpr int Q = SKIPYY ? 4 : 5;          // mu1, mu2, xx, (yy), xy

    const int tid = threadIdx.x;
    const int ox0 = NARROW ? 0 : bx * TW;
    const int oy0 = by * TH;
    const long base = (long)img * N * N;

    // ================= phase 1: batch load ==================================
    const int c  = tid & 127;      // tile-local column 0..127
    const int s  = tid >> 7;       // strip 0/1 (rows 8s .. 8s+7 of v)
    const int ci = ox0 + c;        // global column
    constexpr int half = N >> 1;
    const int powned = NARROW ? N : min(TW, N - ox0);  // pool column ownership

    const float* __restrict__ Xb = X + base;
    const float* __restrict__ Yb = Y + base;

    // interior: no row/col clamping anywhere in this block (block-uniform)
    const bool interior = (oy0 + 25 < N) && (ox0 + 127 < N);

    float xv[18], yv[18];
    if (interior) {
        const float* __restrict__ xp = Xb + (long)(oy0 + 8 * s) * N + ci;
        const float* __restrict__ yp = Yb + (long)(oy0 + 8 * s) * N + ci;
#pragma unroll
        for (int i = 0; i < 18; i++) {
            xv[i] = xp[(long)i * N];
            yv[i] = yp[(long)i * N];
        }
    } else {
        const int cic = min(ci, N - 1);
#pragma unroll
        for (int i = 0; i < 18; i++) {
            int rc = min(oy0 + 8 * s + i, N - 1);
            xv[i] = Xb[(long)rc * N + cic];
            yv[i] = Yb[(long)rc * N + cic];
        }
    }
    __builtin_amdgcn_sched_barrier(0);

    if (SIG) {
#pragma unroll
        for (int i = 0; i < 18; i++) xv[i] = fsig(xv[i]);
    }

    // ================= phase 1b: vertical filter ============================
    float a0[8], a1[8], a2[8], a4[8];
    float a3[SKIPYY ? 1 : 8];
#pragma unroll
    for (int o = 0; o < 8; o++) {
        a0[o] = a1[o] = a2[o] = a4[o] = 0.f;
        if constexpr (!SKIPYY) a3[o] = 0.f;
    }

#pragma unroll
    for (int i = 0; i < 18; i++) {
        float x = xv[i], y = yv[i];
        float xx = x * x, xy = x * y;
#pragma unroll
        for (int o = 0; o < 8; o++) {
            int t = i - o;
            if (t >= 0 && t < 11) {          // folds statically after unroll
                a0[o] = fmaf(W[t], x,  a0[o]);
                a1[o] = fmaf(W[t], y,  a1[o]);
                a2[o] = fmaf(W[t], xx, a2[o]);
                if constexpr (!SKIPYY) a3[o] = fmaf(W[t], y * y, a3[o]);
                a4[o] = fmaf(W[t], xy, a4[o]);
            }
        }
    }

    // ================= phase 1c: fused 2x2 pool (batched shuffles) ==========
    if (POOL) {
        float cx[4], cy[4];
#pragma unroll
        for (int p = 0; p < 4; p++) {
            cx[p] = xv[2 * p] + xv[2 * p + 1];
            cy[p] = yv[2 * p] + yv[2 * p + 1];
        }
#pragma unroll
        for (int p = 0; p < 4; p++) {
            float rx = __shfl_down(cx[p], 1, 64);   // column c+1 (same wave)
            float ry = __shfl_down(cy[p], 1, 64);
            if (!(c & 1) && c < powned) {
                int orow = (oy0 + 8 * s + 2 * p) >> 1;
                int ocol = ci >> 1;
                long pb = (long)img * half * half + (long)orow * half + ocol;
                poolX[pb] = 0.25f * (cx[p] + rx);
                poolY[pb] = 0.25f * (cy[p] + ry);
            }
        }
    }

    // store v to LDS, column-swizzled by 4*row to spread b128 read banks
#pragma unroll
    for (int o = 0; o < 8; o++) {
        int r = 8 * s + o;
        int cc = (c + 4 * r) & 127;
        smem[0 * 2048 + r * 128 + cc] = a0[o];
        smem[1 * 2048 + r * 128 + cc] = a1[o];
        smem[2 * 2048 + r * 128 + cc] = a2[o];
        if constexpr (!SKIPYY) smem[3 * 2048 + r * 128 + cc] = a3[o];
        smem[(Q - 1) * 2048 + r * 128 + cc] = a4[o];
    }
    __syncthreads();

    // ================= phase 2: horizontal filter + SSIM ====================
    const float C1 = 1e-4f, C2 = 9e-4f;
    float scs = 0.f, sss = 0.f;
    {
        const int r = tid >> 4;    // output row within tile
        const int k = tid & 15;    // 8-px column segment
        if (k < 15) {              // segment base 8k must be < 118
            float acc[Q][8];
#pragma unroll
            for (int q = 0; q < Q; q++) {
                float rg[20];
#pragma unroll
                for (int j5 = 0; j5 < 5; j5++) {
                    int col = (8 * k + 4 * j5 + 4 * r) & 127;   // swizzled chunk
                    const float4 v4 = *(const float4*)&smem[q * 2048 + r * 128 + col];
                    rg[4 * j5 + 0] = v4.x; rg[4 * j5 + 1] = v4.y;
                    rg[4 * j5 + 2] = v4.z; rg[4 * j5 + 3] = v4.w;
                }
#pragma unroll
                for (int j = 0; j < 8; j++) {
                    float a = 0.f;
#pragma unroll
                    for (int t = 0; t < 11; t++) a = fmaf(W[t], rg[j + t], a);
                    acc[q][j] = a;
                }
            }
            const int gy = oy0 + r;
            const bool rowok = gy < M;
#pragma unroll
            for (int j = 0; j < 8; j++) {
                int lc = 8 * k + j;
                int gx = ox0 + lc;
                if (lc < TW && gx < M && rowok) {
                    float mu1 = acc[0][j], mu2 = acc[1][j];
                    float exx = acc[2][j], exy = acc[Q - 1][j];
                    float m11 = mu1 * mu1, m22 = mu2 * mu2, m12 = mu1 * mu2;
                    float s1 = exx - m11;
                    float s2 = SKIPYY ? (mu2 - m22) : (acc[3][j] - m22);
                    float s12 = exy - m12;
                    float cs = (2.f * s12 + C2) * frcp(s1 + s2 + C2);
                    float ssim = (2.f * m12 + C1) * frcp(m11 + m22 + C1) * cs;
                    scs += cs; sss += ssim;
                }
            }
        }
    }

    // block reduction (reuse smem after barrier)
    for (int off = 32; off > 0; off >>= 1) {
        scs += __shfl_down(scs, off, 64);
        sss += __shfl_down(sss, off, 64);
    }
    __syncthreads();
    int lane = tid & 63, wv = tid >> 6;
    if (lane == 0) { smem[wv] = scs; smem[4 + wv] = sss; }
    __syncthreads();
    if (tid == 0) {
        atomicAdd(&accCs[img],   smem[0] + smem[1] + smem[2] + smem[3]);
        atomicAdd(&accSsim[img], smem[4] + smem[5] + smem[6] + smem[7]);
    }
}

// ---------------------------------------------------------------------------
// Persistent-block level driver: loop blocks over all tiles of one level.
// ---------------------------------------------------------------------------
template <int N, int M, bool SIG, bool POOL, bool SKIPYY, bool NARROW>
__device__ __forceinline__ void run_level(
    const float* __restrict__ X, const float* __restrict__ Y,
    float* __restrict__ aS, float* __restrict__ aC,
    float* __restrict__ pX, float* __restrict__ pY,
    float* smem, int bid, int nb) {
    constexpr int GX = (N + TW - 1) / TW;
    constexpr int GY = N / TH;
    constexpr int GXY = GX * GY;
    constexpr int NT = GXY * NIMG;
    for (int t = bid; t < NT; t += nb) {
        int img = t / GXY;
        int r = t - img * GXY;
        int by = r / GX;
        int bx = r - by * GX;
        __syncthreads();   // protect smem from previous tile's reduction reads
        ssim_tile<N, M, SIG, POOL, SKIPYY, NARROW>(X, Y, aS, aC, pX, pY,
                                                  img, bx, by, smem);
    }
}

// acc layout: level l -> [l*2*NIMG .. +NIMG) ssim sums, [+NIMG .. +2*NIMG) cs sums
__device__ __forceinline__ void finalize_device(const float* __restrict__ acc,
                                                float* __restrict__ out,
                                                float* smem) {
    const float wts[5] = {0.0448f, 0.2856f, 0.3001f, 0.2363f, 0.1333f};
    const int Ms[5] = {502, 246, 118, 54, 22};
    int t = threadIdx.x;
    float v = 0.f;
    if (t < NIMG) {
        float prod = 1.f;
#pragma unroll
        for (int l = 0; l < 5; l++) {
            float inv = 1.0f / ((float)Ms[l] * (float)Ms[l]);
            float m = (l < 4) ? acc[l * 2 * NIMG + NIMG + t] * inv   // cs mean
                              : acc[l * 2 * NIMG + t] * inv;          // ssim mean
            m = fmaxf(m, 0.f);                                        // relu
            prod *= powf(m, wts[l]);
        }
        v = prod;
    }
    for (int off = 32; off > 0; off >>= 1) v += __shfl_down(v, off, 64);
    __syncthreads();
    if ((t & 63) == 0) smem[t >> 6] = v;   // 4 waves -> smem[0..3]
    __syncthreads();
    if (t == 0)
        out[0] = 1.0f - (smem[0] + smem[1] + smem[2] + smem[3]) / (float)NIMG;
}

// ---------------------------------------------------------------------------
// Mega kernel: all 5 pyramid levels + finalize in ONE cooperative launch.
// Removes 6 dependent dispatch boundaries (ramp/drain + barrier-packet gaps,
// est. ~130 µs of the 421 µs total). grid.sync() between levels; threadfence
// makes plain pool stores device-visible across XCDs before the sync.
// ---------------------------------------------------------------------------
__global__ __launch_bounds__(256, 4)
void ssim_mega(const float* __restrict__ X0, const float* __restrict__ Y0,
               float* acc,
               float* X1, float* Y1, float* X2, float* Y2,
               float* X3, float* Y3, float* X4, float* Y4,
               float* out) {
    __shared__ float smem[5 * 16 * 128];   // 40960 B -> exactly 4 blocks/CU
    cg::grid_group grid = cg::this_grid();
    const int bid = blockIdx.x;
    const int nb = gridDim.x;

    run_level<512, 502, true, true, true, false>(X0, Y0, acc, acc + NIMG, X1, Y1, smem, bid, nb);
    __threadfence(); grid.sync();
    run_level<256, 246, false, true, false, false>(X1, Y1, acc + 2 * NIMG, acc + 3 * NIMG, X2, Y2, smem, bid, nb);
    __threadfence(); grid.sync();
    run_level<128, 118, false, true, false, true>(X2, Y2, acc + 4 * NIMG, acc + 5 * NIMG, X3, Y3, smem, bid, nb);
    __threadfence(); grid.sync();
    run_level<64, 54, false, true, false, true>(X3, Y3, acc + 6 * NIMG, acc + 7 * NIMG, X4, Y4, smem, bid, nb);
    __threadfence(); grid.sync();
    run_level<32, 22, false, false, false, true>(X4, Y4, acc + 8 * NIMG, acc + 9 * NIMG, nullptr, nullptr, smem, bid, nb);
    __threadfence(); grid.sync();

    if (bid == 0) finalize_device(acc, out, smem);
}

// ---------------------------------------------------------------------------
// Fallback path: original per-level kernels (used only if cooperative launch
// is unavailable/rejected — guarantees no regression vs the 421 µs baseline).
// ---------------------------------------------------------------------------
template <int N, int M, bool SIG, bool POOL, bool SKIPYY, bool NARROW>
__global__ __launch_bounds__(256, 4)
void ssim_kernel(const float* __restrict__ X, const float* __restrict__ Y,
                 float* __restrict__ accSsim, float* __restrict__ accCs,
                 float* __restrict__ poolX, float* __restrict__ poolY) {
    __shared__ float smem[5 * 16 * 128];
    ssim_tile<N, M, SIG, POOL, SKIPYY, NARROW>(X, Y, accSsim, accCs, poolX, poolY,
                                               blockIdx.z, blockIdx.x, blockIdx.y, smem);
}

__global__ __launch_bounds__(128)
void finalize_kernel(const float* __restrict__ acc, float* __restrict__ out) {
    const float wts[5] = {0.0448f, 0.2856f, 0.3001f, 0.2363f, 0.1333f};
    const int Ms[5] = {502, 246, 118, 54, 22};
    int t = threadIdx.x;
    float v = 0.f;
    if (t < NIMG) {
        float prod = 1.f;
#pragma unroll
        for (int l = 0; l < 5; l++) {
            float inv = 1.0f / ((float)Ms[l] * (float)Ms[l]);
            float m = (l < 4) ? acc[l * 2 * NIMG + NIMG + t] * inv
                              : acc[l * 2 * NIMG + t] * inv;
            m = fmaxf(m, 0.f);
            prod *= powf(m, wts[l]);
        }
        v = prod;
    }
    for (int off = 32; off > 0; off >>= 1) v += __shfl_down(v, off, 64);
    __shared__ float red[2];
    if ((t & 63) == 0) red[t >> 6] = v;
    __syncthreads();
    if (t == 0) out[0] = 1.0f - (red[0] + red[1]) / (float)NIMG;
}

extern "C" void kernel_launch(void* const* d_in, const int* in_sizes, int n_in,
                              void* d_out, int out_size, void* d_ws, size_t ws_size,
                              hipStream_t stream) {
    const float* logits = (const float*)d_in[0];
    const float* targets = (const float*)d_in[1];
    float* out = (float*)d_out;
    float* ws = (float*)d_ws;

    // workspace layout (floats)
    float* acc = ws;                               // 5*2*116 = 1160 floats
    size_t off = 1280;
    float* X1 = ws + off; off += (size_t)NIMG * 256 * 256;
    float* Y1 = ws + off; off += (size_t)NIMG * 256 * 256;
    float* X2 = ws + off; off += (size_t)NIMG * 128 * 128;
    float* Y2 = ws + off; off += (size_t)NIMG * 128 * 128;
    float* X3 = ws + off; off += (size_t)NIMG * 64 * 64;
    float* Y3 = ws + off; off += (size_t)NIMG * 64 * 64;
    float* X4 = ws + off; off += (size_t)NIMG * 32 * 32;
    float* Y4 = ws + off; off += (size_t)NIMG * 32 * 32;

    hipMemsetAsync(acc, 0, 1160 * sizeof(float), stream);

    // One-time host-side sizing for the cooperative grid (host queries only,
    // no stream ops — safe under graph capture; results cached in statics).
    static int coopGrid = -1;   // -1 = unqueried, 0 = cooperative path disabled
    if (coopGrid < 0) {
        int numCU = 256;
        hipDeviceProp_t prop;
        if (hipGetDeviceProperties(&prop, 0) == hipSuccess && prop.multiProcessorCount > 0)
            numCU = prop.multiProcessorCount;
        int bpc = 0;
        hipError_t e = hipOccupancyMaxActiveBlocksPerMultiprocessor(
            &bpc, (const void*)ssim_mega, 256, 0);
        if (e != hipSuccess || bpc <= 0) coopGrid = 0;
        else coopGrid = numCU * (bpc > 4 ? 4 : bpc);
    }

    bool done = false;
    if (coopGrid > 0) {
        void* ka[] = {(void*)&logits, (void*)&targets, (void*)&acc,
                      (void*)&X1, (void*)&Y1, (void*)&X2, (void*)&Y2,
                      (void*)&X3, (void*)&Y3, (void*)&X4, (void*)&Y4,
                      (void*)&out};
        hipError_t e = hipLaunchCooperativeKernel((const void*)ssim_mega,
                                                  dim3(coopGrid), dim3(256),
                                                  ka, 0, stream);
        if (e == hipSuccess) done = true;
        else coopGrid = 0;   // permanently fall back
    }

    if (!done) {
        {
            dim3 grid((512 + TW - 1) / TW, 512 / TH, NIMG);
            ssim_kernel<512, 502, true, true, true, false><<<grid, 256, 0, stream>>>(
                logits, targets, acc, acc + NIMG, X1, Y1);
        }
        {
            dim3 grid((256 + TW - 1) / TW, 256 / TH, NIMG);
            ssim_kernel<256, 246, false, true, false, false><<<grid, 256, 0, stream>>>(
                X1, Y1, acc + 2 * NIMG, acc + 3 * NIMG, X2, Y2);
        }
        {
            dim3 grid(1, 128 / TH, NIMG);
            ssim_kernel<128, 118, false, true, false, true><<<grid, 256, 0, stream>>>(
                X2, Y2, acc + 4 * NIMG, acc + 5 * NIMG, X3, Y3);
        }
        {
            dim3 grid(1, 64 / TH, NIMG);
            ssim_kernel<64, 54, false, true, false, true><<<grid, 256, 0, stream>>>(
                X3, Y3, acc + 6 * NIMG, acc + 7 * NIMG, X4, Y4);
        }
        {
            dim3 grid(1, 32 / TH, NIMG);
            ssim_kernel<32, 22, false, false, false, true><<<grid, 256, 0, stream>>>(
                X4, Y4, acc + 8 * NIMG, acc + 9 * NIMG, nullptr, nullptr);
        }
        finalize_kernel<<<1, 128, 0, stream>>>(acc, out);
    }
}

// Round 4
// 455.692 us; speedup vs baseline: 2.1535x; 2.1535x over previous
//
#include <hip/hip_runtime.h>
#include <math.h>

#define NIMG 116          // 4*29 images
#define TW 118            // output tile width  (phase-1 columns = TW+10 = 128)
#define TH 16             // output tile height (strips of 8 rows, 2 strips)

// 11-tap Gaussian (size=11, sigma=1.5), fp32 values matching the reference.
static constexpr float W[11] = {
    0.00102838f, 0.00759876f, 0.03600078f, 0.10936075f, 0.21300554f,
    0.26601172f, 0.21300554f, 0.10936075f, 0.03600078f, 0.00759876f,
    0.00102838f};

__device__ __forceinline__ float frcp(float x) {
    return __builtin_amdgcn_rcpf(x);
}

__device__ __forceinline__ float fsig(float x) {
    float e = __builtin_amdgcn_exp2f(x * -1.4426950408889634f);
    return frcp(1.0f + e);
}

// ---------------------------------------------------------------------------
// Per-tile SSIM body (R0's proven 421 µs math; no keep-alive asm — R1 measured
// it costs ~5 µs on level 0 with no VGPR change: 36 loads already fit in
// VGPR=56 and batch fine under sched_barrier alone).
// Phase 1: batch-load 18 rows/thread, vertical Gaussian of {X,Y,XX,(YY),XY};
// fused 2x2 pool from live registers. Phase 2: horizontal Gaussian from LDS
// via swizzled float4 reads + SSIM map + block reduction + atomicAdd.
// N, M compile-time (R1: ~5 µs gain on small levels from folded addressing).
// SKIPYY: binary targets -> filter(YY)==filter(Y). NARROW: N<=128, one x-tile.
// LDS padded to 40960 B -> exactly 4 blocks/CU (R4: locality beats occupancy).
// ---------------------------------------------------------------------------
template <int N, int M, bool SIG, bool POOL, bool SKIPYY, bool NARROW>
__device__ __forceinline__ void ssim_tile(
    const float* __restrict__ X, const float* __restrict__ Y,
    float* __restrict__ accSsim, float* __restrict__ accCs,
    float* __restrict__ poolX, float* __restrict__ poolY,
    int img, int bx, int by, float* smem) {
    constexpr int Q = SKIPYY ? 4 : 5;          // mu1, mu2, xx, (yy), xy

    const int tid = threadIdx.x;
    const int ox0 = NARROW ? 0 : bx * TW;
    const int oy0 = by * TH;
    const long base = (long)img * N * N;

    // ================= phase 1: batch load ==================================
    const int c  = tid & 127;      // tile-local column 0..127
    const int s  = tid >> 7;       // strip 0/1 (rows 8s .. 8s+7 of v)
    const int ci = ox0 + c;        // global column
    constexpr int half = N >> 1;
    const int powned = NARROW ? N : min(TW, N - ox0);  // pool column ownership

    const float* __restrict__ Xb = X + base;
    const float* __restrict__ Yb = Y + base;

    // interior: no row/col clamping anywhere in this block (block-uniform)
    const bool interior = (oy0 + 25 < N) && (ox0 + 127 < N);

    float xv[18], yv[18];
    if (interior) {
        const float* __restrict__ xp = Xb + (long)(oy0 + 8 * s) * N + ci;
        const float* __restrict__ yp = Yb + (long)(oy0 + 8 * s) * N + ci;
#pragma unroll
        for (int i = 0; i < 18; i++) {
            xv[i] = xp[(long)i * N];
            yv[i] = yp[(long)i * N];
        }
    } else {
        const int cic = min(ci, N - 1);
#pragma unroll
        for (int i = 0; i < 18; i++) {
            int rc = min(oy0 + 8 * s + i, N - 1);
            xv[i] = Xb[(long)rc * N + cic];
            yv[i] = Yb[(long)rc * N + cic];
        }
    }
    __builtin_amdgcn_sched_barrier(0);

    if (SIG) {
#pragma unroll
        for (int i = 0; i < 18; i++) xv[i] = fsig(xv[i]);
    }

    // ================= phase 1b: vertical filter ============================
    float a0[8], a1[8], a2[8], a4[8];
    float a3[SKIPYY ? 1 : 8];
#pragma unroll
    for (int o = 0; o < 8; o++) {
        a0[o] = a1[o] = a2[o] = a4[o] = 0.f;
        if constexpr (!SKIPYY) a3[o] = 0.f;
    }

#pragma unroll
    for (int i = 0; i < 18; i++) {
        float x = xv[i], y = yv[i];
        float xx = x * x, xy = x * y;
#pragma unroll
        for (int o = 0; o < 8; o++) {
            int t = i - o;
            if (t >= 0 && t < 11) {          // folds statically after unroll
                a0[o] = fmaf(W[t], x,  a0[o]);
                a1[o] = fmaf(W[t], y,  a1[o]);
                a2[o] = fmaf(W[t], xx, a2[o]);
                if constexpr (!SKIPYY) a3[o] = fmaf(W[t], y * y, a3[o]);
                a4[o] = fmaf(W[t], xy, a4[o]);
            }
        }
    }

    // ================= phase 1c: fused 2x2 pool (batched shuffles) ==========
    if (POOL) {
        float cx[4], cy[4];
#pragma unroll
        for (int p = 0; p < 4; p++) {
            cx[p] = xv[2 * p] + xv[2 * p + 1];
            cy[p] = yv[2 * p] + yv[2 * p + 1];
        }
#pragma unroll
        for (int p = 0; p < 4; p++) {
            float rx = __shfl_down(cx[p], 1, 64);   // column c+1 (same wave)
            float ry = __shfl_down(cy[p], 1, 64);
            if (!(c & 1) && c < powned) {
                int orow = (oy0 + 8 * s + 2 * p) >> 1;
                int ocol = ci >> 1;
                long pb = (long)img * half * half + (long)orow * half + ocol;
                poolX[pb] = 0.25f * (cx[p] + rx);
                poolY[pb] = 0.25f * (cy[p] + ry);
            }
        }
    }

    // store v to LDS, column-swizzled by 4*row to spread b128 read banks
#pragma unroll
    for (int o = 0; o < 8; o++) {
        int r = 8 * s + o;
        int cc = (c + 4 * r) & 127;
        smem[0 * 2048 + r * 128 + cc] = a0[o];
        smem[1 * 2048 + r * 128 + cc] = a1[o];
        smem[2 * 2048 + r * 128 + cc] = a2[o];
        if constexpr (!SKIPYY) smem[3 * 2048 + r * 128 + cc] = a3[o];
        smem[(Q - 1) * 2048 + r * 128 + cc] = a4[o];
    }
    __syncthreads();

    // ================= phase 2: horizontal filter + SSIM ====================
    const float C1 = 1e-4f, C2 = 9e-4f;
    float scs = 0.f, sss = 0.f;
    {
        const int r = tid >> 4;    // output row within tile
        const int k = tid & 15;    // 8-px column segment
        if (k < 15) {              // segment base 8k must be < 118
            float acc[Q][8];
#pragma unroll
            for (int q = 0; q < Q; q++) {
                float rg[20];
#pragma unroll
                for (int j5 = 0; j5 < 5; j5++) {
                    int col = (8 * k + 4 * j5 + 4 * r) & 127;   // swizzled chunk
                    const float4 v4 = *(const float4*)&smem[q * 2048 + r * 128 + col];
                    rg[4 * j5 + 0] = v4.x; rg[4 * j5 + 1] = v4.y;
                    rg[4 * j5 + 2] = v4.z; rg[4 * j5 + 3] = v4.w;
                }
#pragma unroll
                for (int j = 0; j < 8; j++) {
                    float a = 0.f;
#pragma unroll
                    for (int t = 0; t < 11; t++) a = fmaf(W[t], rg[j + t], a);
                    acc[q][j] = a;
                }
            }
            const int gy = oy0 + r;
            const bool rowok = gy < M;          // uniform per thread, hoisted
#pragma unroll
            for (int j = 0; j < 8; j++) {
                int lc = 8 * k + j;
                int gx = ox0 + lc;
                if (lc < TW && gx < M && rowok) {
                    float mu1 = acc[0][j], mu2 = acc[1][j];
                    float exx = acc[2][j], exy = acc[Q - 1][j];
                    float m11 = mu1 * mu1, m22 = mu2 * mu2, m12 = mu1 * mu2;
                    float s1 = exx - m11;
                    float s2 = SKIPYY ? (mu2 - m22) : (acc[3][j] - m22);
                    float s12 = exy - m12;
                    float cs = (2.f * s12 + C2) * frcp(s1 + s2 + C2);
                    float ssim = (2.f * m12 + C1) * frcp(m11 + m22 + C1) * cs;
                    scs += cs; sss += ssim;
                }
            }
        }
    }

    // block reduction (reuse smem after barrier)
    for (int off = 32; off > 0; off >>= 1) {
        scs += __shfl_down(scs, off, 64);
        sss += __shfl_down(sss, off, 64);
    }
    __syncthreads();
    int lane = tid & 63, wv = tid >> 6;
    if (lane == 0) { smem[wv] = scs; smem[4 + wv] = sss; }
    __syncthreads();
    if (tid == 0) {
        atomicAdd(&accCs[img],   smem[0] + smem[1] + smem[2] + smem[3]);
        atomicAdd(&accSsim[img], smem[4] + smem[5] + smem[6] + smem[7]);
    }
}

// ---------------------------------------------------------------------------
// Grid kernels for levels 0 and 1 (unchanged structure — proven 421 µs path).
// ---------------------------------------------------------------------------
template <int N, int M, bool SIG, bool POOL, bool SKIPYY, bool NARROW>
__global__ __launch_bounds__(256, 4)
void ssim_kernel(const float* __restrict__ X, const float* __restrict__ Y,
                 float* __restrict__ accSsim, float* __restrict__ accCs,
                 float* __restrict__ poolX, float* __restrict__ poolY) {
    __shared__ float smem[5 * 16 * 128];       // 40960 B -> 4 blocks/CU
    ssim_tile<N, M, SIG, POOL, SKIPYY, NARROW>(X, Y, accSsim, accCs, poolX, poolY,
                                               blockIdx.z, blockIdx.x, blockIdx.y, smem);
}

// ---------------------------------------------------------------------------
// Tail kernel: one block per image runs levels 2-4 sequentially.
// All pool data at levels >=2 is image-private, so every producer/consumer
// pair lives in the SAME workgroup: __syncthreads() gives correct visibility
// (no cross-XCD hazard — R2's grid.sync approach raced, absmax 0.0117).
// Finalize stays a separate kernel: dispatch-boundary coherence is the
// proven-correct mechanism (baseline absmax 0.0), and the in-kernel ticket
// variant is the only untested piece of the R3 run that failed infra-side.
// ---------------------------------------------------------------------------
template <int N, int M, bool POOL>
__device__ __forceinline__ void tail_level(
    const float* __restrict__ X, const float* __restrict__ Y,
    float* __restrict__ aS, float* __restrict__ aC,
    float* __restrict__ pX, float* __restrict__ pY,
    int img, float* smem) {
    constexpr int GY = N / TH;
#pragma unroll 1
    for (int by = 0; by < GY; ++by) {
        __syncthreads();   // protect smem reuse across tiles
        ssim_tile<N, M, false, POOL, false, true>(X, Y, aS, aC, pX, pY,
                                                  img, 0, by, smem);
    }
}

__global__ __launch_bounds__(256, 4)
void tail_kernel(const float* __restrict__ X2, const float* __restrict__ Y2,
                 float* __restrict__ X3, float* __restrict__ Y3,
                 float* __restrict__ X4, float* __restrict__ Y4,
                 float* __restrict__ acc) {
    __shared__ float smem[5 * 16 * 128];
    const int img = blockIdx.x;

    // level 2: N=128 -> 8 tiles, pools into X3/Y3 (image-private)
    tail_level<128, 118, true>(X2, Y2, acc + 4 * NIMG, acc + 5 * NIMG, X3, Y3, img, smem);
    __syncthreads();
    // level 3: N=64 -> 4 tiles, pools into X4/Y4
    tail_level<64, 54, true>(X3, Y3, acc + 6 * NIMG, acc + 7 * NIMG, X4, Y4, img, smem);
    __syncthreads();
    // level 4: N=32 -> 2 tiles, no pool
    tail_level<32, 22, false>(X4, Y4, acc + 8 * NIMG, acc + 9 * NIMG, nullptr, nullptr, img, smem);
}

// acc layout: level l -> [l*2*NIMG .. +NIMG) ssim sums, [+NIMG .. +2*NIMG) cs sums
__global__ __launch_bounds__(128)
void finalize_kernel(const float* __restrict__ acc, float* __restrict__ out) {
    const float wts[5] = {0.0448f, 0.2856f, 0.3001f, 0.2363f, 0.1333f};
    const int Ms[5] = {502, 246, 118, 54, 22};
    int t = threadIdx.x;
    float v = 0.f;
    if (t < NIMG) {
        float prod = 1.f;
#pragma unroll
        for (int l = 0; l < 5; l++) {
            float inv = 1.0f / ((float)Ms[l] * (float)Ms[l]);
            float m = (l < 4) ? acc[l * 2 * NIMG + NIMG + t] * inv   // cs mean
                              : acc[l * 2 * NIMG + t] * inv;          // ssim mean
            m = fmaxf(m, 0.f);                                        // relu
            prod *= powf(m, wts[l]);
        }
        v = prod;
    }
    for (int off = 32; off > 0; off >>= 1) v += __shfl_down(v, off, 64);
    __shared__ float red[2];
    if ((t & 63) == 0) red[t >> 6] = v;
    __syncthreads();
    if (t == 0) out[0] = 1.0f - (red[0] + red[1]) / (float)NIMG;
}

extern "C" void kernel_launch(void* const* d_in, const int* in_sizes, int n_in,
                              void* d_out, int out_size, void* d_ws, size_t ws_size,
                              hipStream_t stream) {
    const float* logits = (const float*)d_in[0];
    const float* targets = (const float*)d_in[1];
    float* out = (float*)d_out;
    float* ws = (float*)d_ws;

    // workspace layout (floats)
    float* acc = ws;                               // 5*2*116 = 1160 floats
    size_t off = 1280;
    float* X1 = ws + off; off += (size_t)NIMG * 256 * 256;
    float* Y1 = ws + off; off += (size_t)NIMG * 256 * 256;
    float* X2 = ws + off; off += (size_t)NIMG * 128 * 128;
    float* Y2 = ws + off; off += (size_t)NIMG * 128 * 128;
    float* X3 = ws + off; off += (size_t)NIMG * 64 * 64;
    float* Y3 = ws + off; off += (size_t)NIMG * 64 * 64;
    float* X4 = ws + off; off += (size_t)NIMG * 32 * 32;
    float* Y4 = ws + off; off += (size_t)NIMG * 32 * 32;

    hipMemsetAsync(acc, 0, 1160 * sizeof(float), stream);

    // level 0: sigmoid + pool fused, binary targets -> SKIPYY
    {
        dim3 grid((512 + TW - 1) / TW, 512 / TH, NIMG);
        ssim_kernel<512, 502, true, true, true, false><<<grid, 256, 0, stream>>>(
            logits, targets, acc, acc + NIMG, X1, Y1);
    }
    // level 1: N=256, wide tiles
    {
        dim3 grid((256 + TW - 1) / TW, 256 / TH, NIMG);
        ssim_kernel<256, 246, false, true, false, false><<<grid, 256, 0, stream>>>(
            X1, Y1, acc + 2 * NIMG, acc + 3 * NIMG, X2, Y2);
    }
    // levels 2-4: one block per image, tiles sequential in-block
    tail_kernel<<<dim3(NIMG), 256, 0, stream>>>(X2, Y2, X3, Y3, X4, Y4, acc);

    finalize_kernel<<<1, 128, 0, stream>>>(acc, out);
}

// Round 5
// 424.525 us; speedup vs baseline: 2.3116x; 1.0734x over previous
//
#include <hip/hip_runtime.h>
#include <math.h>

#define NIMG 116          // 4*29 images
#define TW 118            // output tile width  (phase-1 columns = TW+10 = 128)
#define TH 16             // output tile height (strips of 8 rows, 2 strips)

// 11-tap Gaussian (size=11, sigma=1.5), fp32 values matching the reference.
static constexpr float W[11] = {
    0.00102838f, 0.00759876f, 0.03600078f, 0.10936075f, 0.21300554f,
    0.26601172f, 0.21300554f, 0.10936075f, 0.03600078f, 0.00759876f,
    0.00102838f};

typedef float f2 __attribute__((ext_vector_type(2)));

__device__ __forceinline__ f2 pkfma(f2 a, f2 b, f2 c) {
#if __has_builtin(__builtin_elementwise_fma)
    return __builtin_elementwise_fma(a, b, c);
#else
    f2 r; r.x = fmaf(a.x, b.x, c.x); r.y = fmaf(a.y, b.y, c.y); return r;
#endif
}

__device__ __forceinline__ float frcp(float x) {
    return __builtin_amdgcn_rcpf(x);
}

__device__ __forceinline__ float fsig(float x) {
    float e = __builtin_amdgcn_exp2f(x * -1.4426950408889634f);
    return frcp(1.0f + e);
}

// ---------------------------------------------------------------------------
// Per-tile SSIM body, packed-FP32 version (targets v_pk_fma_f32 / VOP3P).
// Quantities are processed as pairs: plane01 = {mu1,mu2}=W⊛{x,y},
// plane23 = {xx,xy}=W⊛{x*x,x*y}; x,y live interleaved in f2 from the load on,
// so every 11-tap FMA is one packed op (352 -> 176 per phase per thread).
// yy (non-SKIPYY only) keeps the old scalar path (5th quantity is odd).
// LDS: plane01/plane23 quantity-interleaved f2 (float4 read = 2 cols x 2 q),
// yy scalar plane; 10240 floats = 40960 B -> exactly 4 blocks/CU (R4 note:
// 32 KB -> 5 blocks/CU raises HBM traffic 12%; locality beats occupancy).
// History: R1 keep-alive asm: -5 µs regression, reverted. R2 grid.sync: raced
// (absmax 0.0117). R4 tail_kernel serialization: +35 µs, reverted. Launch
// structure = proven 5 launches + finalize.
// ---------------------------------------------------------------------------
template <int N, int M, bool SIG, bool POOL, bool SKIPYY, bool NARROW>
__device__ __forceinline__ void ssim_tile(
    const float* __restrict__ X, const float* __restrict__ Y,
    float* __restrict__ accSsim, float* __restrict__ accCs,
    float* __restrict__ poolX, float* __restrict__ poolY,
    int img, int bx, int by, float* smem) {
    const int tid = threadIdx.x;
    const int ox0 = NARROW ? 0 : bx * TW;
    const int oy0 = by * TH;
    const long base = (long)img * N * N;

    // ================= phase 1: batch load ==================================
    const int c  = tid & 127;      // tile-local column 0..127
    const int s  = tid >> 7;       // strip 0/1 (rows 8s .. 8s+7 of v)
    const int ci = ox0 + c;        // global column
    constexpr int half = N >> 1;
    const int powned = NARROW ? N : min(TW, N - ox0);  // pool column ownership

    const float* __restrict__ Xb = X + base;
    const float* __restrict__ Yb = Y + base;

    // interior: no row/col clamping anywhere in this block (block-uniform)
    const bool interior = (oy0 + 25 < N) && (ox0 + 127 < N);

    f2 xy[18];                     // .x = X row value, .y = Y row value
    if (interior) {
        const float* __restrict__ xp = Xb + (long)(oy0 + 8 * s) * N + ci;
        const float* __restrict__ yp = Yb + (long)(oy0 + 8 * s) * N + ci;
#pragma unroll
        for (int i = 0; i < 18; i++) {
            xy[i].x = xp[(long)i * N];
            xy[i].y = yp[(long)i * N];
        }
    } else {
        const int cic = min(ci, N - 1);
#pragma unroll
        for (int i = 0; i < 18; i++) {
            int rc = min(oy0 + 8 * s + i, N - 1);
            xy[i].x = Xb[(long)rc * N + cic];
            xy[i].y = Yb[(long)rc * N + cic];
        }
    }
    __builtin_amdgcn_sched_barrier(0);

    if (SIG) {
#pragma unroll
        for (int i = 0; i < 18; i++) xy[i].x = fsig(xy[i].x);
    }

    // ================= phase 1b: vertical filter (packed) ===================
    f2 a01[8], a23[8];
    float ayy[SKIPYY ? 1 : 8];
#pragma unroll
    for (int o = 0; o < 8; o++) {
        a01[o] = (f2){0.f, 0.f};
        a23[o] = (f2){0.f, 0.f};
        if constexpr (!SKIPYY) ayy[o] = 0.f;
    }

#pragma unroll
    for (int i = 0; i < 18; i++) {
        f2 v01 = xy[i];
        f2 xb = (f2){v01.x, v01.x};
        f2 v23 = xb * v01;                       // {x*x, x*y} via v_pk_mul
        float yy;
        if constexpr (!SKIPYY) yy = v01.y * v01.y;
#pragma unroll
        for (int o = 0; o < 8; o++) {
            int t = i - o;
            if (t >= 0 && t < 11) {              // folds statically after unroll
                f2 w = (f2){W[t], W[t]};
                a01[o] = pkfma(w, v01, a01[o]);
                a23[o] = pkfma(w, v23, a23[o]);
                if constexpr (!SKIPYY) ayy[o] = fmaf(W[t], yy, ayy[o]);
            }
        }
    }

    // ================= phase 1c: fused 2x2 pool (batched shuffles) ==========
    if (POOL) {
        float cx[4], cy[4];
#pragma unroll
        for (int p = 0; p < 4; p++) {
            cx[p] = xy[2 * p].x + xy[2 * p + 1].x;
            cy[p] = xy[2 * p].y + xy[2 * p + 1].y;
        }
#pragma unroll
        for (int p = 0; p < 4; p++) {
            float rx = __shfl_down(cx[p], 1, 64);   // column c+1 (same wave)
            float ry = __shfl_down(cy[p], 1, 64);
            if (!(c & 1) && c < powned) {
                int orow = (oy0 + 8 * s + 2 * p) >> 1;
                int ocol = ci >> 1;
                long pb = (long)img * half * half + (long)orow * half + ocol;
                poolX[pb] = 0.25f * (cx[p] + rx);
                poolY[pb] = 0.25f * (cy[p] + ry);
            }
        }
    }

    // store to LDS, column-swizzled by 4*row; planes 0/1 are f2-interleaved
    // (plane01 floats [0,4096), plane23 [4096,8192), yy scalar [8192,10240))
#pragma unroll
    for (int o = 0; o < 8; o++) {
        int r = 8 * s + o;
        int cc = (c + 4 * r) & 127;
        *(f2*)&smem[0 * 4096 + r * 256 + cc * 2] = a01[o];
        *(f2*)&smem[1 * 4096 + r * 256 + cc * 2] = a23[o];
        if constexpr (!SKIPYY) smem[8192 + r * 128 + cc] = ayy[o];
    }
    __syncthreads();

    // ================= phase 2: horizontal filter + SSIM ====================
    const float C1 = 1e-4f, C2 = 9e-4f;
    float scs = 0.f, sss = 0.f;
    {
        const int r = tid >> 4;    // output row within tile
        const int k = tid & 15;    // 8-px column segment
        if (k < 15) {              // segment base 8k must be < 118
            f2 o01[8], o23[8];
            float oyy[8];
            // ---- packed planes: {mu1,mu2} then {xx,xy} --------------------
#pragma unroll
            for (int pl = 0; pl < 2; pl++) {
                f2 rg[18];
#pragma unroll
                for (int m = 0; m < 9; m++) {
                    int scol = (8 * k + 2 * m + 4 * r) & 127;   // even -> f4 aligned
                    const float4 v4 = *(const float4*)&smem[pl * 4096 + r * 256 + scol * 2];
                    rg[2 * m]     = (f2){v4.x, v4.y};
                    rg[2 * m + 1] = (f2){v4.z, v4.w};
                }
#pragma unroll
                for (int j = 0; j < 8; j++) {
                    f2 a = (f2){0.f, 0.f};
#pragma unroll
                    for (int t = 0; t < 11; t++) {
                        f2 w = (f2){W[t], W[t]};
                        a = pkfma(w, rg[j + t], a);
                    }
                    if (pl == 0) o01[j] = a; else o23[j] = a;
                }
            }
            // ---- scalar yy plane (non-SKIPYY only) ------------------------
            if constexpr (!SKIPYY) {
                float rgs[20];
#pragma unroll
                for (int j5 = 0; j5 < 5; j5++) {
                    int col = (8 * k + 4 * j5 + 4 * r) & 127;
                    const float4 v4 = *(const float4*)&smem[8192 + r * 128 + col];
                    rgs[4 * j5 + 0] = v4.x; rgs[4 * j5 + 1] = v4.y;
                    rgs[4 * j5 + 2] = v4.z; rgs[4 * j5 + 3] = v4.w;
                }
#pragma unroll
                for (int j = 0; j < 8; j++) {
                    float a = 0.f;
#pragma unroll
                    for (int t = 0; t < 11; t++) a = fmaf(W[t], rgs[j + t], a);
                    oyy[j] = a;
                }
            }
            const int gy = oy0 + r;
            const bool rowok = gy < M;          // uniform per thread, hoisted
#pragma unroll
            for (int j = 0; j < 8; j++) {
                int lc = 8 * k + j;
                int gx = ox0 + lc;
                if (lc < TW && gx < M && rowok) {
                    float mu1 = o01[j].x, mu2 = o01[j].y;
                    float exx = o23[j].x, exy = o23[j].y;
                    float m11 = mu1 * mu1, m22 = mu2 * mu2, m12 = mu1 * mu2;
                    float s1 = exx - m11;
                    float s2 = SKIPYY ? (mu2 - m22) : (oyy[j] - m22);
                    float s12 = exy - m12;
                    float cs = (2.f * s12 + C2) * frcp(s1 + s2 + C2);
                    float ssim = (2.f * m12 + C1) * frcp(m11 + m22 + C1) * cs;
                    scs += cs; sss += ssim;
                }
            }
        }
    }

    // block reduction (reuse smem after barrier)
    for (int off = 32; off > 0; off >>= 1) {
        scs += __shfl_down(scs, off, 64);
        sss += __shfl_down(sss, off, 64);
    }
    __syncthreads();
    int lane = tid & 63, wv = tid >> 6;
    if (lane == 0) { smem[wv] = scs; smem[4 + wv] = sss; }
    __syncthreads();
    if (tid == 0) {
        atomicAdd(&accCs[img],   smem[0] + smem[1] + smem[2] + smem[3]);
        atomicAdd(&accSsim[img], smem[4] + smem[5] + smem[6] + smem[7]);
    }
}

// ---------------------------------------------------------------------------
// Grid kernels (proven 5-launch structure).
// ---------------------------------------------------------------------------
template <int N, int M, bool SIG, bool POOL, bool SKIPYY, bool NARROW>
__global__ __launch_bounds__(256, 4)
void ssim_kernel(const float* __restrict__ X, const float* __restrict__ Y,
                 float* __restrict__ accSsim, float* __restrict__ accCs,
                 float* __restrict__ poolX, float* __restrict__ poolY) {
    __shared__ float smem[10240];              // 40960 B -> 4 blocks/CU
    ssim_tile<N, M, SIG, POOL, SKIPYY, NARROW>(X, Y, accSsim, accCs, poolX, poolY,
                                               blockIdx.z, blockIdx.x, blockIdx.y, smem);
}

// acc layout: level l -> [l*2*NIMG .. +NIMG) ssim sums, [+NIMG .. +2*NIMG) cs sums
__global__ __launch_bounds__(128)
void finalize_kernel(const float* __restrict__ acc, float* __restrict__ out) {
    const float wts[5] = {0.0448f, 0.2856f, 0.3001f, 0.2363f, 0.1333f};
    const int Ms[5] = {502, 246, 118, 54, 22};
    int t = threadIdx.x;
    float v = 0.f;
    if (t < NIMG) {
        float prod = 1.f;
#pragma unroll
        for (int l = 0; l < 5; l++) {
            float inv = 1.0f / ((float)Ms[l] * (float)Ms[l]);
            float m = (l < 4) ? acc[l * 2 * NIMG + NIMG + t] * inv   // cs mean
                              : acc[l * 2 * NIMG + t] * inv;          // ssim mean
            m = fmaxf(m, 0.f);                                        // relu
            prod *= powf(m, wts[l]);
        }
        v = prod;
    }
    for (int off = 32; off > 0; off >>= 1) v += __shfl_down(v, off, 64);
    __shared__ float red[2];
    if ((t & 63) == 0) red[t >> 6] = v;
    __syncthreads();
    if (t == 0) out[0] = 1.0f - (red[0] + red[1]) / (float)NIMG;
}

extern "C" void kernel_launch(void* const* d_in, const int* in_sizes, int n_in,
                              void* d_out, int out_size, void* d_ws, size_t ws_size,
                              hipStream_t stream) {
    const float* logits = (const float*)d_in[0];
    const float* targets = (const float*)d_in[1];
    float* out = (float*)d_out;
    float* ws = (float*)d_ws;

    // workspace layout (floats)
    float* acc = ws;                               // 5*2*116 = 1160 floats
    size_t off = 1280;
    float* X1 = ws + off; off += (size_t)NIMG * 256 * 256;
    float* Y1 = ws + off; off += (size_t)NIMG * 256 * 256;
    float* X2 = ws + off; off += (size_t)NIMG * 128 * 128;
    float* Y2 = ws + off; off += (size_t)NIMG * 128 * 128;
    float* X3 = ws + off; off += (size_t)NIMG * 64 * 64;
    float* Y3 = ws + off; off += (size_t)NIMG * 64 * 64;
    float* X4 = ws + off; off += (size_t)NIMG * 32 * 32;
    float* Y4 = ws + off; off += (size_t)NIMG * 32 * 32;

    hipMemsetAsync(acc, 0, 1160 * sizeof(float), stream);

    // level 0: sigmoid + pool fused, binary targets -> SKIPYY
    {
        dim3 grid((512 + TW - 1) / TW, 512 / TH, NIMG);
        ssim_kernel<512, 502, true, true, true, false><<<grid, 256, 0, stream>>>(
            logits, targets, acc, acc + NIMG, X1, Y1);
    }
    // level 1: N=256, wide tiles
    {
        dim3 grid((256 + TW - 1) / TW, 256 / TH, NIMG);
        ssim_kernel<256, 246, false, true, false, false><<<grid, 256, 0, stream>>>(
            X1, Y1, acc + 2 * NIMG, acc + 3 * NIMG, X2, Y2);
    }
    // level 2: N=128, single x-tile
    {
        dim3 grid(1, 128 / TH, NIMG);
        ssim_kernel<128, 118, false, true, false, true><<<grid, 256, 0, stream>>>(
            X2, Y2, acc + 4 * NIMG, acc + 5 * NIMG, X3, Y3);
    }
    // level 3: N=64, single x-tile
    {
        dim3 grid(1, 64 / TH, NIMG);
        ssim_kernel<64, 54, false, true, false, true><<<grid, 256, 0, stream>>>(
            X3, Y3, acc + 6 * NIMG, acc + 7 * NIMG, X4, Y4);
    }
    // level 4: N=32, single x-tile, no pool
    {
        dim3 grid(1, 32 / TH, NIMG);
        ssim_kernel<32, 22, false, false, false, true><<<grid, 256, 0, stream>>>(
            X4, Y4, acc + 8 * NIMG, acc + 9 * NIMG, nullptr, nullptr);
    }

    finalize_kernel<<<1, 128, 0, stream>>>(acc, out);
}

// Round 6
// 414.465 us; speedup vs baseline: 2.3677x; 1.0243x over previous
//
#include <hip/hip_runtime.h>
#include <math.h>

#define NIMG 116          // 4*29 images
#define TW 118            // output tile width  (phase-1 columns = TW+10 = 128)
#define TH 16             // output tile height (strips of 8 rows, 2 strips)

// 11-tap Gaussian (size=11, sigma=1.5), fp32 values matching the reference.
static constexpr float W[11] = {
    0.00102838f, 0.00759876f, 0.03600078f, 0.10936075f, 0.21300554f,
    0.26601172f, 0.21300554f, 0.10936075f, 0.03600078f, 0.00759876f,
    0.00102838f};

typedef float f2 __attribute__((ext_vector_type(2)));

__device__ __forceinline__ f2 pkfma(f2 a, f2 b, f2 c) {
#if __has_builtin(__builtin_elementwise_fma)
    return __builtin_elementwise_fma(a, b, c);
#else
    f2 r; r.x = fmaf(a.x, b.x, c.x); r.y = fmaf(a.y, b.y, c.y); return r;
#endif
}

__device__ __forceinline__ float frcp(float x) {
    return __builtin_amdgcn_rcpf(x);
}

__device__ __forceinline__ float fsig(float x) {
    float e = __builtin_amdgcn_exp2f(x * -1.4426950408889634f);
    return frcp(1.0f + e);
}

// ---------------------------------------------------------------------------
// Per-tile SSIM body, packed-FP32 + bank-swizzled LDS.
// R5 lesson: pkfma cut VALU issue 80->58% busy but LDS conflicts jumped
// 8M->20M (f2 interleave => 8-way within-row aliasing) — net zero. R6 keeps
// the packing and fixes banks:
//   main plane: one float4 COLUMN per tile col = {mu1,mu2,xx,xy}, placed at
//   phys = col ^ ((col>>3 + row)&7). Per b128 instruction the 64 lanes land
//   8/bank-group = the hardware floor (uniform), for both reads and writes.
//   yy plane (non-SKIPYY): scalar plane with f4-chunk XOR swizzle (2-way).
// LDS: plane 16r x 128c x 4q = 8192 floats; yy 2048 floats -> 40960 B total
// -> exactly 4 blocks/CU (R4: 32 KB/5 blocks raises HBM 12%; keep locality).
// History: R1 keep-alive asm -5 µs reverted; R2 grid.sync raced; R4 tail
// serialization +35 µs reverted. Launch structure = proven 5 + finalize.
// ---------------------------------------------------------------------------
template <int N, int M, bool SIG, bool POOL, bool SKIPYY, bool NARROW>
__device__ __forceinline__ void ssim_tile(
    const float* __restrict__ X, const float* __restrict__ Y,
    float* __restrict__ accSsim, float* __restrict__ accCs,
    float* __restrict__ poolX, float* __restrict__ poolY,
    int img, int bx, int by, float* smem) {
    const int tid = threadIdx.x;
    const int ox0 = NARROW ? 0 : bx * TW;
    const int oy0 = by * TH;
    const long base = (long)img * N * N;

    // ================= phase 1: batch load ==================================
    const int c  = tid & 127;      // tile-local column 0..127
    const int s  = tid >> 7;       // strip 0/1 (rows 8s .. 8s+7 of v)
    const int ci = ox0 + c;        // global column
    constexpr int half = N >> 1;
    const int powned = NARROW ? N : min(TW, N - ox0);  // pool column ownership

    const float* __restrict__ Xb = X + base;
    const float* __restrict__ Yb = Y + base;

    // interior: no row/col clamping anywhere in this block (block-uniform)
    const bool interior = (oy0 + 25 < N) && (ox0 + 127 < N);

    f2 xy[18];                     // .x = X row value, .y = Y row value
    if (interior) {
        const float* __restrict__ xp = Xb + (long)(oy0 + 8 * s) * N + ci;
        const float* __restrict__ yp = Yb + (long)(oy0 + 8 * s) * N + ci;
#pragma unroll
        for (int i = 0; i < 18; i++) {
            xy[i].x = xp[(long)i * N];
            xy[i].y = yp[(long)i * N];
        }
    } else {
        const int cic = min(ci, N - 1);
#pragma unroll
        for (int i = 0; i < 18; i++) {
            int rc = min(oy0 + 8 * s + i, N - 1);
            xy[i].x = Xb[(long)rc * N + cic];
            xy[i].y = Yb[(long)rc * N + cic];
        }
    }
    __builtin_amdgcn_sched_barrier(0);

    if (SIG) {
#pragma unroll
        for (int i = 0; i < 18; i++) xy[i].x = fsig(xy[i].x);
    }

    // ================= phase 1b: vertical filter (packed) ===================
    f2 a01[8], a23[8];
    float ayy[SKIPYY ? 1 : 8];
#pragma unroll
    for (int o = 0; o < 8; o++) {
        a01[o] = (f2){0.f, 0.f};
        a23[o] = (f2){0.f, 0.f};
        if constexpr (!SKIPYY) ayy[o] = 0.f;
    }

#pragma unroll
    for (int i = 0; i < 18; i++) {
        f2 v01 = xy[i];
        f2 xb = (f2){v01.x, v01.x};
        f2 v23 = xb * v01;                       // {x*x, x*y} packed mul
        float yy;
        if constexpr (!SKIPYY) yy = v01.y * v01.y;
#pragma unroll
        for (int o = 0; o < 8; o++) {
            int t = i - o;
            if (t >= 0 && t < 11) {              // folds statically after unroll
                f2 w = (f2){W[t], W[t]};
                a01[o] = pkfma(w, v01, a01[o]);
                a23[o] = pkfma(w, v23, a23[o]);
                if constexpr (!SKIPYY) ayy[o] = fmaf(W[t], yy, ayy[o]);
            }
        }
    }

    // ================= phase 1c: fused 2x2 pool (batched shuffles) ==========
    if (POOL) {
        float cx[4], cy[4];
#pragma unroll
        for (int p = 0; p < 4; p++) {
            cx[p] = xy[2 * p].x + xy[2 * p + 1].x;
            cy[p] = xy[2 * p].y + xy[2 * p + 1].y;
        }
#pragma unroll
        for (int p = 0; p < 4; p++) {
            float rx = __shfl_down(cx[p], 1, 64);   // column c+1 (same wave)
            float ry = __shfl_down(cy[p], 1, 64);
            if (!(c & 1) && c < powned) {
                int orow = (oy0 + 8 * s + 2 * p) >> 1;
                int ocol = ci >> 1;
                long pb = (long)img * half * half + (long)orow * half + ocol;
                poolX[pb] = 0.25f * (cx[p] + rx);
                poolY[pb] = 0.25f * (cy[p] + ry);
            }
        }
    }

    // ---- LDS write: float4 column {mu1,mu2,xx,xy} at XOR-swizzled position
    // main plane floats [0,8192); yy scalar plane [8192,10240)
#pragma unroll
    for (int o = 0; o < 8; o++) {
        int rr = 8 * s + o;
        int phys = c ^ (((c >> 3) + rr) & 7);           // bijective per row
        float4 v;
        v.x = a01[o].x; v.y = a01[o].y; v.z = a23[o].x; v.w = a23[o].y;
        *(float4*)&smem[rr * 512 + phys * 4] = v;
        if constexpr (!SKIPYY) {
            int ch = c >> 2;
            int pc = ch ^ (((ch >> 3) + rr) & 7);       // f4-chunk swizzle
            smem[8192 + rr * 128 + pc * 4 + (c & 3)] = ayy[o];
        }
    }
    __syncthreads();

    // ================= phase 2: horizontal filter + SSIM ====================
    const float C1 = 1e-4f, C2 = 9e-4f;
    float scs = 0.f, sss = 0.f;
    {
        const int r = tid >> 4;    // output row within tile
        const int k = tid & 15;    // 8-px column segment
        if (k < 15) {              // segment base 8k must be < 118
            f2 a01h[8], a23h[8];
#pragma unroll
            for (int j = 0; j < 8; j++) {
                a01h[j] = (f2){0.f, 0.f};
                a23h[j] = (f2){0.f, 0.f};
            }
            // accumulate-on-load: one f4 read delivers all 4 quantities of a
            // column; rg value is dead after its 8 (j,t) uses -> low liveness
#pragma unroll
            for (int m = 0; m < 18; m++) {
                int col = 8 * k + m;                    // may be 128/129 @k=14
                int g = (k + (m >> 3) + r) & 7;         // == ((col>>3)+r)&7
                int phys = (col ^ g) & 127;             // wrap: garbage masked
                const float4 v4 = *(const float4*)&smem[r * 512 + phys * 4];
                f2 v01 = (f2){v4.x, v4.y};
                f2 v23 = (f2){v4.z, v4.w};
#pragma unroll
                for (int j = 0; j < 8; j++) {
                    int t = m - j;
                    if (t >= 0 && t < 11) {             // folds statically
                        f2 w = (f2){W[t], W[t]};
                        a01h[j] = pkfma(w, v01, a01h[j]);
                        a23h[j] = pkfma(w, v23, a23h[j]);
                    }
                }
            }
            // ---- scalar yy plane (non-SKIPYY only) ------------------------
            float oyy[8];
            if constexpr (!SKIPYY) {
                float rgs[20];
#pragma unroll
                for (int j5 = 0; j5 < 5; j5++) {
                    int ch = 2 * k + j5;                // may be 32 @k=14
                    int pc = (ch ^ (((ch >> 3) + r) & 7)) & 31;
                    const float4 v4 = *(const float4*)&smem[8192 + r * 128 + pc * 4];
                    rgs[4 * j5 + 0] = v4.x; rgs[4 * j5 + 1] = v4.y;
                    rgs[4 * j5 + 2] = v4.z; rgs[4 * j5 + 3] = v4.w;
                }
#pragma unroll
                for (int j = 0; j < 8; j++) {
                    float a = 0.f;
#pragma unroll
                    for (int t = 0; t < 11; t++) a = fmaf(W[t], rgs[j + t], a);
                    oyy[j] = a;
                }
            }
            const int gy = oy0 + r;
            const bool rowok = gy < M;          // uniform per thread, hoisted
#pragma unroll
            for (int j = 0; j < 8; j++) {
                int lc = 8 * k + j;
                int gx = ox0 + lc;
                if (lc < TW && gx < M && rowok) {
                    float mu1 = a01h[j].x, mu2 = a01h[j].y;
                    float exx = a23h[j].x, exy = a23h[j].y;
                    float m11 = mu1 * mu1, m22 = mu2 * mu2, m12 = mu1 * mu2;
                    float s1 = exx - m11;
                    float s2 = SKIPYY ? (mu2 - m22) : (oyy[j] - m22);
                    float s12 = exy - m12;
                    float cs = (2.f * s12 + C2) * frcp(s1 + s2 + C2);
                    float ssim = (2.f * m12 + C1) * frcp(m11 + m22 + C1) * cs;
                    scs += cs; sss += ssim;
                }
            }
        }
    }

    // block reduction (reuse smem after barrier)
    for (int off = 32; off > 0; off >>= 1) {
        scs += __shfl_down(scs, off, 64);
        sss += __shfl_down(sss, off, 64);
    }
    __syncthreads();
    int lane = tid & 63, wv = tid >> 6;
    if (lane == 0) { smem[wv] = scs; smem[4 + wv] = sss; }
    __syncthreads();
    if (tid == 0) {
        atomicAdd(&accCs[img],   smem[0] + smem[1] + smem[2] + smem[3]);
        atomicAdd(&accSsim[img], smem[4] + smem[5] + smem[6] + smem[7]);
    }
}

// ---------------------------------------------------------------------------
// Grid kernels (proven 5-launch structure).
// ---------------------------------------------------------------------------
template <int N, int M, bool SIG, bool POOL, bool SKIPYY, bool NARROW>
__global__ __launch_bounds__(256, 4)
void ssim_kernel(const float* __restrict__ X, const float* __restrict__ Y,
                 float* __restrict__ accSsim, float* __restrict__ accCs,
                 float* __restrict__ poolX, float* __restrict__ poolY) {
    __shared__ float smem[10240];              // 40960 B -> 4 blocks/CU
    ssim_tile<N, M, SIG, POOL, SKIPYY, NARROW>(X, Y, accSsim, accCs, poolX, poolY,
                                               blockIdx.z, blockIdx.x, blockIdx.y, smem);
}

// acc layout: level l -> [l*2*NIMG .. +NIMG) ssim sums, [+NIMG .. +2*NIMG) cs sums
__global__ __launch_bounds__(128)
void finalize_kernel(const float* __restrict__ acc, float* __restrict__ out) {
    const float wts[5] = {0.0448f, 0.2856f, 0.3001f, 0.2363f, 0.1333f};
    const int Ms[5] = {502, 246, 118, 54, 22};
    int t = threadIdx.x;
    float v = 0.f;
    if (t < NIMG) {
        float prod = 1.f;
#pragma unroll
        for (int l = 0; l < 5; l++) {
            float inv = 1.0f / ((float)Ms[l] * (float)Ms[l]);
            float m = (l < 4) ? acc[l * 2 * NIMG + NIMG + t] * inv   // cs mean
                              : acc[l * 2 * NIMG + t] * inv;          // ssim mean
            m = fmaxf(m, 0.f);                                        // relu
            prod *= powf(m, wts[l]);
        }
        v = prod;
    }
    for (int off = 32; off > 0; off >>= 1) v += __shfl_down(v, off, 64);
    __shared__ float red[2];
    if ((t & 63) == 0) red[t >> 6] = v;
    __syncthreads();
    if (t == 0) out[0] = 1.0f - (red[0] + red[1]) / (float)NIMG;
}

extern "C" void kernel_launch(void* const* d_in, const int* in_sizes, int n_in,
                              void* d_out, int out_size, void* d_ws, size_t ws_size,
                              hipStream_t stream) {
    const float* logits = (const float*)d_in[0];
    const float* targets = (const float*)d_in[1];
    float* out = (float*)d_out;
    float* ws = (float*)d_ws;

    // workspace layout (floats)
    float* acc = ws;                               // 5*2*116 = 1160 floats
    size_t off = 1280;
    float* X1 = ws + off; off += (size_t)NIMG * 256 * 256;
    float* Y1 = ws + off; off += (size_t)NIMG * 256 * 256;
    float* X2 = ws + off; off += (size_t)NIMG * 128 * 128;
    float* Y2 = ws + off; off += (size_t)NIMG * 128 * 128;
    float* X3 = ws + off; off += (size_t)NIMG * 64 * 64;
    float* Y3 = ws + off; off += (size_t)NIMG * 64 * 64;
    float* X4 = ws + off; off += (size_t)NIMG * 32 * 32;
    float* Y4 = ws + off; off += (size_t)NIMG * 32 * 32;

    hipMemsetAsync(acc, 0, 1160 * sizeof(float), stream);

    // level 0: sigmoid + pool fused, binary targets -> SKIPYY
    {
        dim3 grid((512 + TW - 1) / TW, 512 / TH, NIMG);
        ssim_kernel<512, 502, true, true, true, false><<<grid, 256, 0, stream>>>(
            logits, targets, acc, acc + NIMG, X1, Y1);
    }
    // level 1: N=256, wide tiles
    {
        dim3 grid((256 + TW - 1) / TW, 256 / TH, NIMG);
        ssim_kernel<256, 246, false, true, false, false><<<grid, 256, 0, stream>>>(
            X1, Y1, acc + 2 * NIMG, acc + 3 * NIMG, X2, Y2);
    }
    // level 2: N=128, single x-tile
    {
        dim3 grid(1, 128 / TH, NIMG);
        ssim_kernel<128, 118, false, true, false, true><<<grid, 256, 0, stream>>>(
            X2, Y2, acc + 4 * NIMG, acc + 5 * NIMG, X3, Y3);
    }
    // level 3: N=64, single x-tile
    {
        dim3 grid(1, 64 / TH, NIMG);
        ssim_kernel<64, 54, false, true, false, true><<<grid, 256, 0, stream>>>(
            X3, Y3, acc + 6 * NIMG, acc + 7 * NIMG, X4, Y4);
    }
    // level 4: N=32, single x-tile, no pool
    {
        dim3 grid(1, 32 / TH, NIMG);
        ssim_kernel<32, 22, false, false, false, true><<<grid, 256, 0, stream>>>(
            X4, Y4, acc + 8 * NIMG, acc + 9 * NIMG, nullptr, nullptr);
    }

    finalize_kernel<<<1, 128, 0, stream>>>(acc, out);
}